// Round 11
// baseline (3743.621 us; speedup 1.0000x reference)
//
#include <hip/hip_runtime.h>
#include <cstdint>
#include <cstddef>

#define NB 256   // batch
#define NT 512   // time steps
#define ND 64    // input dim
#define NH 512   // hidden dim
#define NG 1366  // granules per block-chunk: ceil(4096 halves / 3)

typedef __attribute__((ext_vector_type(8))) _Float16 half8;
typedef __attribute__((ext_vector_type(4))) float f32x4;
typedef unsigned long long ull;

__device__ __forceinline__ float tanh_fast(float x) {
  float ax = fabsf(x);
  float e  = __expf(-2.0f * ax);
  float t  = (1.0f - e) * __frcp_rn(1.0f + e);
  return copysignf(t, x);
}

// Pack W (W_hh | W_ih) to fp16 fragment-major (same as R10):
//   unit u = ((kt*4 + cb)*8 + j)*64 + lane, 8 halves each.
__global__ void prep_kernel(const float* __restrict__ whh,
                            const float* __restrict__ wih,
                            _Float16* __restrict__ wpk) {
  const int id = blockIdx.x * 256 + threadIdx.x;   // 0..36863
  if (id >= 18 * 4 * 8 * 64) return;
  const int lane = id & 63;
  const int j    = (id >> 6) & 7;
  const int cbv  = (id >> 9) & 3;
  const int kt   = id >> 11;
  const int n    = cbv * 128 + j * 16 + (lane & 15);
  const int kb   = kt * 32 + (lane >> 4) * 8;
  half8 o;
#pragma unroll
  for (int e = 0; e < 8; ++e) {
    const int k = kb + e;
    const float v = (kt < 16) ? whh[(size_t)n * NH + k]
                              : wih[(size_t)n * ND + (k - NH)];
    o[e] = (_Float16)v;
  }
  *(half8*)(wpk + (size_t)id * 8) = o;
}

// Zero all granule tags (fresh every call -> no stale-tag false-match).
__global__ void init_kernel(ull* __restrict__ hg) {
  int i = blockIdx.x * 256 + threadIdx.x;
  if (i < 2 * 16 * 4 * NG) hg[i] = 0ull;
}

// out[b][t] = b_ho + sum_cb partial[cb][b][t]
__global__ void combine_kernel(const float* __restrict__ partial,
                               const float* __restrict__ bho,
                               float* __restrict__ out) {
  int id = blockIdx.x * 256 + threadIdx.x;   // 131072
  out[id] = bho[0] + partial[id] + partial[id + NB * NT]
          + partial[id + 2 * NB * NT] + partial[id + 3 * NB * NT];
}

// Column-split persistent RNN, fp16, tagged-granule exchange:
// 64 blocks (16 bg x 4 cb) x 4 waves; block = 16 rows x 128 cols.
// W fp16 stationary (kt0..7 LDS, kt8..17 VGPR). h fp16 hi+lo split.
// Exchange: 8B granules = 3 halves + 16-bit step tag, relaxed agent
// atomics. NO flags, NO vmcnt drains: tag+data atomic in one 8B store.
// Consumer batch-issues all loads, batch-retries stale ones.
__global__ __launch_bounds__(256, 1) void rnn_f16(
    const float* __restrict__ x, const _Float16* __restrict__ wpk,
    const float* __restrict__ bih, const float* __restrict__ bhh,
    const float* __restrict__ who,
    ull* __restrict__ hglob,        // [2][16 bg][4 cb][NG] granules
    float* __restrict__ partial)    // [4 cb][NB][NT] f32
{
  __shared__ _Float16 wlds[8][8][64][8];      // 64 KiB: W kt 0..7
  __shared__ _Float16 hpeer[2][2][16][520];   // 65 KiB: [buf][plane][row][col]
  __shared__ _Float16 tstage[4][2][16][40];   // 10 KiB
  __shared__ float posum[4][16];

  const int bid  = blockIdx.x;
  const int bg   = bid >> 2;
  const int cb   = bid & 3;
  const int w    = threadIdx.x >> 6;
  const int lane = threadIdx.x & 63;
  const int lm   = lane & 15;
  const int lg   = lane >> 4;
  const int lkb  = lg * 8;
  const int bm   = bg * 16;
  const int n0   = cb * 128 + w * 32;

  // ---- W kt 0..7 -> LDS ----
  for (int i = threadIdx.x; i < 8 * 8 * 64; i += 256) {
    const int kt = i >> 9, jj = (i >> 6) & 7, ln = i & 63;
    const _Float16* src = wpk + (size_t)(((kt * 4 + cb) * 8 + jj) * 64 + ln) * 8;
    *(half8*)&wlds[kt][jj][ln][0] = *(const half8*)src;
  }
  // ---- W kt 8..15 + x-tiles -> VGPRs ----
  half8 wreg[8][2], wx[2][2];
#pragma unroll
  for (int q = 0; q < 8; ++q)
#pragma unroll
    for (int nt = 0; nt < 2; ++nt)
      wreg[q][nt] = *(const half8*)(wpk +
        (size_t)((((q + 8) * 4 + cb) * 8 + (w * 2 + nt)) * 64 + lane) * 8);
#pragma unroll
  for (int q = 0; q < 2; ++q)
#pragma unroll
    for (int nt = 0; nt < 2; ++nt)
      wx[q][nt] = *(const half8*)(wpk +
        (size_t)((((q + 16) * 4 + cb) * 8 + (w * 2 + nt)) * 64 + lane) * 8);

  float bv[2], wov[2];
#pragma unroll
  for (int nt = 0; nt < 2; ++nt) {
    const int n = n0 + nt * 16 + lm;
    bv[nt]  = bih[n] + bhh[n];
    wov[nt] = who[n];
  }

  // h(-1) = 0 in hpeer buffer 0
  for (int i = threadIdx.x; i < 2 * 16 * 520 * 2 / 4; i += 256)
    ((unsigned*)&hpeer[0][0][0][0])[i] = 0u;
  __syncthreads();

  const float* xrow = x + (size_t)(bm + lm) * NT * ND + lkb;
  f32x4 xr[4];
#pragma unroll
  for (int xt = 0; xt < 2; ++xt) {
    xr[2 * xt]     = *(const f32x4*)(xrow + xt * 32);
    xr[2 * xt + 1] = *(const f32x4*)(xrow + xt * 32 + 4);
  }

  // fetch-slot granule offsets (relative within a [4][NG] bg region)
  unsigned foff[17];
  unsigned fvalid = 0;
#pragma unroll
  for (int k = 0; k < 17; ++k) {
    const int idx = threadIdx.x + k * 256;
    if (idx < 3 * NG) {
      const int pi  = idx / NG;
      const int g   = idx - pi * NG;
      const int scb = pi + (pi >= cb);
      foff[k] = (unsigned)(scb * NG + g);
      fvalid |= 1u << k;
    } else foff[k] = 0;
  }

  int cur = 0;
  for (int t = 0; t < NT; ++t) {
    const int nxt = cur ^ 1;

    // ---- x(t): fp32 -> fp16 hi/lo split ----
    half8 axh[2], axl[2];
#pragma unroll
    for (int xt = 0; xt < 2; ++xt) {
      float v[8];
      *(f32x4*)&v[0] = xr[2 * xt];
      *(f32x4*)&v[4] = xr[2 * xt + 1];
#pragma unroll
      for (int e = 0; e < 8; ++e) {
        _Float16 hi = (_Float16)v[e];
        axh[xt][e] = hi;
        axl[xt][e] = (_Float16)(v[e] - (float)hi);
      }
    }

    // ---- MFMA: two independent chains (ah, al) per nt ----
    f32x4 acc[2][2];
#pragma unroll
    for (int nt = 0; nt < 2; ++nt) {
      acc[nt][0] = (f32x4){0.f, 0.f, 0.f, 0.f};
      acc[nt][1] = (f32x4){0.f, 0.f, 0.f, 0.f};
    }
#pragma unroll
    for (int kt = 0; kt < 8; ++kt) {
      half8 ah = *(const half8*)&hpeer[cur][0][lm][kt * 32 + lkb];
      half8 al = *(const half8*)&hpeer[cur][1][lm][kt * 32 + lkb];
#pragma unroll
      for (int nt = 0; nt < 2; ++nt) {
        half8 b = *(const half8*)&wlds[kt][w * 2 + nt][lane][0];
        acc[nt][0] = __builtin_amdgcn_mfma_f32_16x16x32_f16(ah, b, acc[nt][0], 0, 0, 0);
        acc[nt][1] = __builtin_amdgcn_mfma_f32_16x16x32_f16(al, b, acc[nt][1], 0, 0, 0);
      }
    }
#pragma unroll
    for (int q = 0; q < 8; ++q) {
      half8 ah = *(const half8*)&hpeer[cur][0][lm][(q + 8) * 32 + lkb];
      half8 al = *(const half8*)&hpeer[cur][1][lm][(q + 8) * 32 + lkb];
#pragma unroll
      for (int nt = 0; nt < 2; ++nt) {
        acc[nt][0] = __builtin_amdgcn_mfma_f32_16x16x32_f16(ah, wreg[q][nt], acc[nt][0], 0, 0, 0);
        acc[nt][1] = __builtin_amdgcn_mfma_f32_16x16x32_f16(al, wreg[q][nt], acc[nt][1], 0, 0, 0);
      }
    }
#pragma unroll
    for (int q = 0; q < 2; ++q)
#pragma unroll
      for (int nt = 0; nt < 2; ++nt) {
        acc[nt][0] = __builtin_amdgcn_mfma_f32_16x16x32_f16(axh[q], wx[q][nt], acc[nt][0], 0, 0, 0);
        acc[nt][1] = __builtin_amdgcn_mfma_f32_16x16x32_f16(axl[q], wx[q][nt], acc[nt][1], 0, 0, 0);
      }

    // ---- epilogue: tanh, split, tstage + own-stage hpeer[nxt], partials ----
    float po[4] = {0.f, 0.f, 0.f, 0.f};
#pragma unroll
    for (int nt = 0; nt < 2; ++nt) {
#pragma unroll
      for (int r = 0; r < 4; ++r) {
        float pre = acc[nt][0][r] + acc[nt][1][r] + bv[nt];
        float hv  = tanh_fast(pre);
        const int m = lg * 4 + r;
        _Float16 hi = (_Float16)hv;
        _Float16 lo = (_Float16)(hv - (float)hi);
        tstage[w][0][m][nt * 16 + lm] = hi;
        tstage[w][1][m][nt * 16 + lm] = lo;
        hpeer[nxt][0][m][n0 + nt * 16 + lm] = hi;
        hpeer[nxt][1][m][n0 + nt * 16 + lm] = lo;
        po[r] += hv * wov[nt];
      }
    }
#pragma unroll
    for (int s = 1; s < 16; s <<= 1)
#pragma unroll
      for (int r = 0; r < 4; ++r) po[r] += __shfl_xor(po[r], s, 64);
    if (lm == 0) {
#pragma unroll
      for (int r = 0; r < 4; ++r) posum[w][lg * 4 + r] = po[r];
    }

    __syncthreads();   // B': tstage/posum complete (no VMEM outstanding)

    const ull tagbits = (ull)(unsigned short)(t + 1) << 48;

    // ---- publish: pack 3 halves + tag per 8B granule, fire-and-forget ----
    if (t + 1 < NT) {
      ull* pub = hglob + (((size_t)((t + 1) & 1) * 16 + bg) * 4 + cb) * NG;
#pragma unroll 2
      for (int g = threadIdx.x; g < NG; g += 256) {
        ull pk = tagbits;
        const int p0 = g * 3;
#pragma unroll
        for (int s = 0; s < 3; ++s) {
          const int p = p0 + s;
          if (p < 4096) {
            const int plane = p >> 11, row = (p >> 7) & 15, col = p & 127;
            const unsigned short hv =
              *(const unsigned short*)&tstage[col >> 5][plane][row][col & 31];
            pk |= (ull)hv << (16 * s);
          }
        }
        __hip_atomic_store(pub + g, pk, __ATOMIC_RELAXED, __HIP_MEMORY_SCOPE_AGENT);
      }
    }

    // out partial (off critical path)
    if (w == 0 && lane < 16) {
      float s = posum[0][lane] + posum[1][lane] + posum[2][lane] + posum[3][lane];
      partial[((size_t)cb * NB + bm + lane) * NT + t] = s;
    }
    // x(t+1) prefetch
    if (t + 1 < NT) {
#pragma unroll
      for (int xt = 0; xt < 2; ++xt) {
        xr[2 * xt]     = *(const f32x4*)(xrow + (size_t)(t + 1) * ND + xt * 32);
        xr[2 * xt + 1] = *(const f32x4*)(xrow + (size_t)(t + 1) * ND + xt * 32 + 4);
      }
    }

    // ---- fetch: batch-issue, batch-retry stale granules, stage to LDS ----
    if (t + 1 < NT) {
      const ull* fb = hglob + (((size_t)((t + 1) & 1) * 16 + bg) * 4) * NG;
      const unsigned short exp_tag = (unsigned short)(t + 1);
      ull vv[17];
#pragma unroll
      for (int k = 0; k < 17; ++k)
        if (fvalid & (1u << k))
          vv[k] = __hip_atomic_load(fb + foff[k], __ATOMIC_RELAXED,
                                    __HIP_MEMORY_SCOPE_AGENT);
      unsigned pend = fvalid;
      for (;;) {
#pragma unroll
        for (int k = 0; k < 17; ++k)
          if ((pend & (1u << k)) && (unsigned short)(vv[k] >> 48) == exp_tag)
            pend &= ~(1u << k);
        if (!pend) break;
        __builtin_amdgcn_s_sleep(1);
#pragma unroll
        for (int k = 0; k < 17; ++k)
          if (pend & (1u << k))
            vv[k] = __hip_atomic_load(fb + foff[k], __ATOMIC_RELAXED,
                                      __HIP_MEMORY_SCOPE_AGENT);
      }
#pragma unroll
      for (int k = 0; k < 17; ++k) {
        if (!(fvalid & (1u << k))) continue;
        const int idx = threadIdx.x + k * 256;
        const int pi  = idx / NG;
        const int g   = idx - pi * NG;
        const int scb = pi + (pi >= cb);
        const int p0  = g * 3;
#pragma unroll
        for (int s = 0; s < 3; ++s) {
          const int p = p0 + s;
          if (p < 4096) {
            const int plane = p >> 11, row = (p >> 7) & 15, col = p & 127;
            *(unsigned short*)&hpeer[nxt][plane][row][scb * 128 + col] =
              (unsigned short)(vv[k] >> (16 * s));
          }
        }
      }
    }

    __syncthreads();   // C: hpeer[nxt] fully staged
    cur = nxt;
  }
}

extern "C" void kernel_launch(void* const* d_in, const int* in_sizes, int n_in,
                              void* d_out, int out_size, void* d_ws, size_t ws_size,
                              hipStream_t stream) {
  const float* x   = (const float*)d_in[0];
  const float* wih = (const float*)d_in[1];
  const float* whh = (const float*)d_in[2];
  const float* bih = (const float*)d_in[3];
  const float* bhh = (const float*)d_in[4];
  const float* who = (const float*)d_in[5];
  const float* bho = (const float*)d_in[6];
  float* out = (float*)d_out;

  // ws: wpk 576KB | hglob granules 700KB | partial 2MB
  _Float16* wpk = (_Float16*)d_ws;
  ull* hglob = (ull*)(wpk + (size_t)18 * 4 * 8 * 64 * 8);
  float* partial = (float*)(hglob + (size_t)2 * 16 * 4 * NG);

  init_kernel<<<683, 256, 0, stream>>>(hglob);
  prep_kernel<<<144, 256, 0, stream>>>(whh, wih, wpk);
  rnn_f16<<<64, 256, 0, stream>>>(x, wpk, bih, bhh, who, hglob, partial);
  combine_kernel<<<512, 256, 0, stream>>>(partial, bho, out);
}